// Round 6
// baseline (1107.964 us; speedup 1.0000x reference)
//
#include <hip/hip_runtime.h>

#define N_IN 128
#define HID 256
#define NB 16
#define BM 128
#define HS2 136          // bf16 row stride for half-K H tile (128 + 8 pad, 16B-aligned rows)

typedef __attribute__((ext_vector_type(8))) short s8v;   // 8 bf16 = 4 VGPRs
typedef __attribute__((ext_vector_type(4))) float f4v;   // MFMA 16x16x32 accumulator

__device__ __forceinline__ unsigned short f2bf(float f) {
  unsigned int u = __float_as_uint(f);
  u += 0x7fffu + ((u >> 16) & 1u);   // round-to-nearest-even
  return (unsigned short)(u >> 16);
}

__device__ __forceinline__ float tanh_fast(float x) {
  float e = __expf(2.0f * x);
  return 1.0f - 2.0f * __builtin_amdgcn_rcpf(e + 1.0f);
}

// Fragment-ordered bf16 repack (1 KB coalesced MFMA fragments), verified rounds 2-5.
// W1f frag (pass,kk,ct): n = pass*128+ct*16+l15, k = kk*32+quad*8+j, val = W1[k*256+n]
// W2f frag (b,kk,ct):    n = ct*16+l15,          k = kk*32+quad*8+j, val = W2[k*2048+n*16+b]
__global__ void prep_kernel(const float* __restrict__ W1, const float* __restrict__ W2,
                            unsigned short* __restrict__ W1f, unsigned short* __restrict__ W2f) {
  int tid = blockIdx.x * blockDim.x + threadIdx.x;
  if (tid < N_IN * HID) {
    int j = tid & 7, lane = (tid >> 3) & 63, ct = (tid >> 9) & 7, kk = (tid >> 12) & 3, pass = tid >> 14;
    int n = pass * 128 + ct * 16 + (lane & 15);
    int k = kk * 32 + (lane >> 4) * 8 + j;
    W1f[tid] = f2bf(W1[k * HID + n]);
  }
  int i = tid - N_IN * HID;
  if (i >= 0 && i < HID * (N_IN * NB)) {
    int j = i & 7, lane = (i >> 3) & 63, ct = (i >> 9) & 7, kk = (i >> 12) & 7, b = i >> 15;
    int n = ct * 16 + (lane & 15);
    int k = kk * 32 + (lane >> 4) * 8 + j;
    W2f[i] = f2bf(W2[k * (N_IN * NB) + n * 16 + b]);
  }
}

__global__ void __launch_bounds__(256, 3)
pilayer_kernel(const float* __restrict__ prop,
               const int* __restrict__ idx_i,
               const int* __restrict__ idx_j,
               const float* __restrict__ basis,
               const unsigned short* __restrict__ W1f,
               const unsigned short* __restrict__ W2f,
               float* __restrict__ out, int P) {
  __shared__ unsigned short Hs[BM * HS2];   // 34,816 B — holds ONE K-half of H at a time
  __shared__ float basisB[NB * BM];         //  8,192 B, b-major  -> 43 KB total, 3 blocks/CU

  const int t = threadIdx.x;
  const int lane = t & 63;
  const int wv = t >> 6;
  const int l15 = lane & 15;
  const int l4 = lane >> 4;
  const int tile0 = blockIdx.x * BM;
  const int rg = wv >> 1, cg = wv & 1;   // 2x2 wave partition for phase C
  const int rbase = rg * 64;

  // ---- stage basis b-major: basisB[b][p_local] ----
  {
    int r = t >> 1;
    int c0 = (t & 1) * 8;
    int p = tile0 + r; if (p >= P) p = P - 1;
    const float4* bp = (const float4*)(basis + (long)p * NB + c0);
    float4 b0 = bp[0], b1 = bp[1];
    basisB[(c0 + 0) * BM + r] = b0.x; basisB[(c0 + 1) * BM + r] = b0.y;
    basisB[(c0 + 2) * BM + r] = b0.z; basisB[(c0 + 3) * BM + r] = b0.w;
    basisB[(c0 + 4) * BM + r] = b1.x; basisB[(c0 + 5) * BM + r] = b1.y;
    basisB[(c0 + 6) * BM + r] = b1.z; basisB[(c0 + 7) * BM + r] = b1.w;
  }

  // gather indices for phase B (wave owns rows [32*wv, 32*wv+32))
  const int row0 = wv * 32;
  int pidx[2], qidx[2];
#pragma unroll
  for (int rt = 0; rt < 2; ++rt) {
    int p = tile0 + row0 + rt * 16 + l15; if (p >= P) p = P - 1;
    pidx[rt] = idx_i[p];
    qidx[rt] = idx_j[p];
  }

  f4v o[4][4];   // persistent output acc: rows rbase+rt*16.., cols (cg*4+q)*16..
#pragma unroll
  for (int rt = 0; rt < 4; ++rt)
#pragma unroll
    for (int q = 0; q < 4; ++q) o[rt][q] = (f4v){0.f, 0.f, 0.f, 0.f};

#pragma unroll 1
  for (int khalf = 0; khalf < 2; ++khalf) {
    // ---- Phase B pass=khalf: H[:, khalf*128 .. +128] -> Hs (wave-local rows) ----
    {
      f4v acc[2][8];
#pragma unroll
      for (int rt = 0; rt < 2; ++rt)
#pragma unroll
        for (int ct = 0; ct < 8; ++ct) acc[rt][ct] = (f4v){0.f, 0.f, 0.f, 0.f};
#pragma unroll
      for (int kk = 0; kk < 4; ++kk) {
        int k0 = kk * 32 + l4 * 8;
        s8v afr[2];
#pragma unroll
        for (int rt = 0; rt < 2; ++rt) {
          const float4* ai = (const float4*)(prop + (long)pidx[rt] * N_IN + k0);
          const float4* aj = (const float4*)(prop + (long)qidx[rt] * N_IN + k0);
          float4 x0 = ai[0], x1 = ai[1];
          float4 y0 = aj[0], y1 = aj[1];
          s8v a;
          a[0] = (short)f2bf(x0.x + y0.x); a[1] = (short)f2bf(x0.y + y0.y);
          a[2] = (short)f2bf(x0.z + y0.z); a[3] = (short)f2bf(x0.w + y0.w);
          a[4] = (short)f2bf(x1.x + y1.x); a[5] = (short)f2bf(x1.y + y1.y);
          a[6] = (short)f2bf(x1.z + y1.z); a[7] = (short)f2bf(x1.w + y1.w);
          afr[rt] = a;
        }
#pragma unroll
        for (int ct = 0; ct < 8; ++ct) {
          s8v bfr = *(const s8v*)(W1f + ((((khalf * 4 + kk) * 8 + ct) * 64 + lane) << 3));
#pragma unroll
          for (int rt = 0; rt < 2; ++rt)
            acc[rt][ct] = __builtin_amdgcn_mfma_f32_16x16x32_bf16(afr[rt], bfr, acc[rt][ct], 0, 0, 0);
        }
      }
#pragma unroll
      for (int rt = 0; rt < 2; ++rt)
#pragma unroll
        for (int ct = 0; ct < 8; ++ct)
#pragma unroll
          for (int r = 0; r < 4; ++r) {
            int lrow = row0 + rt * 16 + l4 * 4 + r;
            int col = ct * 16 + l15;
            Hs[lrow * HS2 + col] = f2bf(tanh_fast(acc[rt][ct][r]));
          }
    }

    __syncthreads();   // Hs(khalf) complete (and basisB, first time)

    // ---- A-cache: 16 fragments of this wave's 64 rows (cross-wave reads) ----
    s8v areg[4][4];
#pragma unroll
    for (int rt = 0; rt < 4; ++rt)
#pragma unroll
      for (int kloc = 0; kloc < 4; ++kloc)
        areg[rt][kloc] = *(const s8v*)&Hs[(rbase + rt * 16 + l15) * HS2 + kloc * 32 + l4 * 8];

    __syncthreads();   // all waves captured aregs; Hs free for next pass

    // ---- Phase C (khalf): B double-buffered from global W2f ----
    s8v bf[2][4];
#pragma unroll
    for (int kloc = 0; kloc < 4; ++kloc)
      bf[0][kloc] = *(const s8v*)(W2f + ((((khalf * 4 + kloc) * 8) + cg * 4) << 9) + lane * 8);

#pragma unroll 1
    for (int b = 0; b < 16; ++b) {
      float4 bs4[4];
#pragma unroll
      for (int rt = 0; rt < 4; ++rt)
        bs4[rt] = *(const float4*)&basisB[b * BM + rbase + rt * 16 + l4 * 4];

#pragma unroll
      for (int q = 0; q < 4; ++q) {
        const int cur = q & 1;
        {
          int nb = (q == 3) ? (b + 1 < 16 ? b + 1 : 15) : b;
          int nq = (q + 1) & 3;
#pragma unroll
          for (int kloc = 0; kloc < 4; ++kloc)
            bf[cur ^ 1][kloc] = *(const s8v*)(W2f +
                (((nb * 8 + khalf * 4 + kloc) * 8 + cg * 4 + nq) << 9) + lane * 8);
        }
        f4v g[4];
#pragma unroll
        for (int rt = 0; rt < 4; ++rt) g[rt] = (f4v){0.f, 0.f, 0.f, 0.f};
#pragma unroll
        for (int kloc = 0; kloc < 4; ++kloc)
#pragma unroll
          for (int rt = 0; rt < 4; ++rt)
            g[rt] = __builtin_amdgcn_mfma_f32_16x16x32_bf16(areg[rt][kloc], bf[cur][kloc], g[rt], 0, 0, 0);
#pragma unroll
        for (int rt = 0; rt < 4; ++rt) {
          o[rt][q][0] += g[rt][0] * bs4[rt].x;
          o[rt][q][1] += g[rt][1] * bs4[rt].y;
          o[rt][q][2] += g[rt][2] * bs4[rt].z;
          o[rt][q][3] += g[rt][3] * bs4[rt].w;
        }
      }
    }
  }

  // ---- epilogue: out[p][c], c = (cg*4+q)*16 + l15 ----
#pragma unroll
  for (int rt = 0; rt < 4; ++rt)
#pragma unroll
    for (int r = 0; r < 4; ++r) {
      int p = tile0 + rbase + rt * 16 + l4 * 4 + r;
      if (p < P) {
        float* op = out + (long)p * N_IN + cg * 64 + l15;
#pragma unroll
        for (int q = 0; q < 4; ++q)
          op[q * 16] = o[rt][q][r];
      }
    }
}

extern "C" void kernel_launch(void* const* d_in, const int* in_sizes, int n_in,
                              void* d_out, int out_size, void* d_ws, size_t ws_size,
                              hipStream_t stream) {
  const float* prop  = (const float*)d_in[0];
  const int* idx_i   = (const int*)d_in[1];
  const int* idx_j   = (const int*)d_in[2];
  const float* basis = (const float*)d_in[3];
  const float* W1    = (const float*)d_in[4];
  const float* W2    = (const float*)d_in[5];
  float* out = (float*)d_out;
  int P = in_sizes[1];

  unsigned short* W1f = (unsigned short*)d_ws;                 // 32768 bf16
  unsigned short* W2f = W1f + N_IN * HID;                      // 524288 bf16

  int prep_threads = N_IN * HID + HID * N_IN * NB;             // 557056
  prep_kernel<<<(prep_threads + 255) / 256, 256, 0, stream>>>(W1, W2, W1f, W2f);

  int ntiles = (P + BM - 1) / BM;
  pilayer_kernel<<<ntiles, 256, 0, stream>>>(prop, idx_i, idx_j, basis, W1f, W2f, out, P);
}